// Round 5
// baseline (416.830 us; speedup 1.0000x reference)
//
#include <hip/hip_runtime.h>
#include <hip/hip_bf16.h>

// Downsample: 3x3 conv (96->48, s1, p1, no bias) + PixelUnshuffle(2), fused.
// x: (8,96,256,256) fp32; W: (48,96,3,3) fp32; out: (8,192,128,128) fp32.
//
// R8 = R7 with LDS sized to the full DMA slot space (32768B: masked-lane
// slots for k=7/wv>=2 now have backing store even though exec-masked lanes
// never write -> no OOB hazard; 160KiB/32KiB = still exactly 5 blocks/CU).
//
// R7 vs R6 (172us, BW 17.7%, latency-bound): reg-staging caps MLP at the
// VGPR budget (issue-8/drain/pack serially). Replace staging with
// global_load_lds DMA: no payload regs, 30KB/block in flight per chunk.
//  - LDS holds fp32 (DMA can't convert); frag assembly converts with
//    v_cvt_pk_bf16_f32 on read (VALU was 11% busy - headroom).
//  - Tile 4x32 (full 64B out lines - fixes R6's 135MB write inflation),
//    halo 6x40 x 32ci fp32 -> 5 blocks/CU, 20 waves.
//  - LDS layout [ci][r][c'] DMA-natural; col rotation c'=(c+8*kg)%40 baked
//    into DMA src addr AND read addr -> frag-read bank conflict exactly
//    2-way (free per m136) instead of 4-way.
//  - Keep R6's XCD-batch swizzle (fetch 275->104MB win), tiles ordered in
//    8x8 blocks within XCD so tx/ty halo neighbors stay L2-close.
//  - Boundary blocks pre-zero LDS once (masked DMA lanes never write;
//    mask pattern identical across the 3 chunks so zeros persist).

typedef __attribute__((ext_vector_type(8))) short bf16x8;   // 8 bf16 (4 VGPRs)
typedef __attribute__((ext_vector_type(4))) float f32x4;    // MFMA C/D
typedef __attribute__((ext_vector_type(4))) unsigned uint4v;

typedef const __attribute__((address_space(1))) void GV;    // global
typedef __attribute__((address_space(3))) void LV;          // LDS

#define CIN 96
#define COUT 48
#define HW 256
#define TH 4                   // out rows per block (1 per wave)
#define TW 32                  // out cols per block
#define HR 6                   // halo rows
#define HCW 40                 // halo col words (fp32): [w0-4 .. w0+35]
#define NRUN 10                // 16B runs per (ci,row)
#define CC 32                  // ci per chunk = one MFMA k-step
#define NTASK (CC * HR * NRUN) // 1920 DMA tasks per chunk
#define NSLOT 2048             // 8 k-iters x 256 threads (backing store)

static __device__ __forceinline__ unsigned bfbits(float f) {
    unsigned u = __builtin_bit_cast(unsigned, f);
    return (u + 0x7fffu + ((u >> 16) & 1u)) >> 16;   // RNE
}
static __device__ __forceinline__ unsigned packbf(float lo, float hi) {
    // emits v_cvt_pk_bf16_f32 (RNE, bit-identical to bfbits pair)
    __hip_bfloat162 h = __float22bfloat162_rn(float2{lo, hi});
    unsigned r;
    __builtin_memcpy(&r, &h, sizeof(r));
    return r;
}

// ---- kernel 1: W (48,96,3,3) fp32 -> MFMA A-frag blob bf16 in d_ws ----
// blob[cc][d][ct][lane][j], cc=ci>>5, d=3x3 tap, ct=co>>4,
// lane=(co&15)|((cl>>3)<<4), j=cl&7   (cl = ci&31). 3*9*3*64*8 halfs = 82944 B
__global__ __launch_bounds__(256) void wtransform(
    const float* __restrict__ Wg, short* __restrict__ blob)
{
    int t = blockIdx.x * 256 + threadIdx.x;          // = (co*96+ci)*9+d
    if (t >= COUT * CIN * 9) return;
    int co  = t / (CIN * 9);
    int rem = t - co * (CIN * 9);
    int ci  = rem / 9;
    int d   = rem - ci * 9;
    int cc  = ci >> 5, cl = ci & 31;
    int ct  = co >> 4;
    int lane = (co & 15) | ((cl >> 3) << 4);
    int j   = cl & 7;
    blob[((((cc * 9 + d) * 3 + ct) * 64 + lane) * 8) + j] = (short)bfbits(Wg[t]);
}

// ---- kernel 2: conv + unshuffle, DMA-staged fp32 LDS ----
__global__ __launch_bounds__(256, 5) void conv3x3_unshuffle_mfma(
    const float* __restrict__ x,
    const short* __restrict__ wblob,
    float* __restrict__ out)
{
    __shared__ float xs[NSLOT * 4];                  // 32768 B (5 blocks/CU)

    const int tid  = threadIdx.x;
    const int lane = tid & 63;
    const int wv   = tid >> 6;                       // wave 0..3 = out row

    // XCD swizzle: XCD = batch; within batch, tiles in 8x8 blocks
    // (tx fast, then ty_lo, then ty_hi) so halo neighbors are L2-close.
    int bid = blockIdx.x;                            // 0..4095
    int b   = bid & 7;                               // batch = XCD
    int t0  = bid >> 3;                              // 0..511
    int ty  = ((t0 >> 6) << 3) | ((t0 >> 3) & 7);    // 0..63
    int tx  = t0 & 7;                                // 0..7
    int h0  = ty * TH;
    int w0  = tx * TW;

    const float* xb = x + (size_t)b * CIN * HW * HW;

    // boundary blocks: pre-zero LDS (masked DMA lanes leave slots untouched;
    // mask pattern is chunk-invariant so zeros persist across all 3 chunks)
    if (ty == 0 || ty == 63 || tx == 0 || tx == 7) {
        for (int i = tid; i < NSLOT; i += 256)
            *(uint4v*)&xs[i * 4] = (uint4v){0u, 0u, 0u, 0u};
        __syncthreads();
    }

    f32x4 acc[2][3];
#pragma unroll
    for (int pt = 0; pt < 2; ++pt)
#pragma unroll
        for (int ct = 0; ct < 3; ++ct)
            acc[pt][ct] = (f32x4){0.f, 0.f, 0.f, 0.f};

    // A-frag prefetch (cc=0, d=0)
    bf16x8 afc[3];
#pragma unroll
    for (int ct = 0; ct < 3; ++ct)
        afc[ct] = *(const bf16x8*)(wblob + ct * 512 + lane * 8);

    for (int cc = 0; cc < CIN / CC; ++cc) {
        // ---- DMA stage: 1920 x 16B tasks; slot t <-> (ci, r, run') ----
        // LDS word W = t*4 + word = ((ci*6 + r)*10 + run')*4 + word.
        // Col rotation: stored c' holds logical col c = (c' - 8*kg) mod 40
        // (kg = ci>>3) -> frag reads spread across banks (exactly 2-way).
#pragma unroll
        for (int k = 0; k < 8; ++k) {
            int t   = tid + k * 256;
            int ci  = t / 60;
            int rem = t - ci * 60;
            int r   = rem / 10;
            int rp  = rem - r * 10;                  // run' (stored position)
            int kg  = ci >> 3;
            int run = rp - 2 * kg; if (run < 0) run += 10;   // logical run
            int gh  = h0 + r - 1;
            int gw0 = w0 - 4 + run * 4;              // 16B-aligned (w0%32==0)
            bool ok = (t < NTASK) & ((unsigned)gh < HW) & ((unsigned)gw0 < (HW - 3));
            const float* src = xb + (((size_t)(cc * CC + ci)) << 16)
                                  + (gh << 8) + gw0;
            if (ok)
                __builtin_amdgcn_global_load_lds((GV*)src,
                    (LV*)(xs + (size_t)(k * 256 + wv * 64) * 4), 16, 0, 0);
        }
        __syncthreads();                 // vmcnt(0) drain + barrier: xs ready

        // ---- 9 shifted GEMM k-steps; convert fp32->bf16 on read ----
        const short* wc = wblob + (size_t)cc * 9 * 3 * 512;   // 512 halfs/frag
#pragma unroll
        for (int d = 0; d < 9; ++d) {
            const short* wn = (d < 8) ? (wc + (d + 1) * 3 * 512)
                                      : (cc < 2 ? wc + 9 * 3 * 512 : wc);
            bf16x8 afn[3];
#pragma unroll
            for (int ct = 0; ct < 3; ++ct)
                afn[ct] = *(const bf16x8*)(wn + ct * 512 + lane * 8);

            const int dy = d / 3, dx = d - 3 * dy;
            const int r  = wv + dy;                  // 0..5
            const int kg = lane >> 4;
            bf16x8 bfv[2];
#pragma unroll
            for (int pt = 0; pt < 2; ++pt) {
                int c  = pt * 16 + (lane & 15) + dx + 3;     // logical col 3..36
                int c2 = c + 8 * kg; if (c2 >= HCW) c2 -= HCW; // stored col
                float f[8];
#pragma unroll
                for (int j = 0; j < 8; ++j)          // pairs merge to ds_read2_b32
                    f[j] = xs[((8 * kg + j) * 6 + r) * 40 + c2];
                uint4v pk;
                pk.x = packbf(f[0], f[1]);
                pk.y = packbf(f[2], f[3]);
                pk.z = packbf(f[4], f[5]);
                pk.w = packbf(f[6], f[7]);
                __builtin_memcpy(&bfv[pt], &pk, 16);
            }
#pragma unroll
            for (int pt = 0; pt < 2; ++pt)
#pragma unroll
                for (int ct = 0; ct < 3; ++ct)
                    acc[pt][ct] = __builtin_amdgcn_mfma_f32_16x16x32_bf16(
                        afc[ct], bfv[pt], acc[pt][ct], 0, 0, 0);
#pragma unroll
            for (int ct = 0; ct < 3; ++ct) afc[ct] = afn[ct];
        }
        if (cc < 2) __syncthreads();     // all reads done before next DMA
    }

    // ---- epilogue: PixelUnshuffle folded into addressing ----
    // C/D layout: col(pix) = lane&15, row(co) = (lane>>4)*4 + reg
    const int oh = h0 + wv;
#pragma unroll
    for (int pt = 0; pt < 2; ++pt) {
        int ow = w0 + pt * 16 + (lane & 15);
        int sub = ((oh & 1) << 1) | (ow & 1);
        size_t pixoff = (size_t)(oh >> 1) * (HW / 2) + (ow >> 1);
#pragma unroll
        for (int ct = 0; ct < 3; ++ct) {
#pragma unroll
            for (int e = 0; e < 4; ++e) {
                int co = ct * 16 + (lane >> 4) * 4 + e;
                out[((size_t)b * (COUT * 4) + co * 4 + sub) * (HW / 2) * (HW / 2) + pixoff] =
                    acc[pt][ct][e];
            }
        }
    }
}

extern "C" void kernel_launch(void* const* d_in, const int* in_sizes, int n_in,
                              void* d_out, int out_size, void* d_ws, size_t ws_size,
                              hipStream_t stream) {
    const float* x  = (const float*)d_in[0];   // 8*96*256*256
    const float* Wg = (const float*)d_in[1];   // 48*96*3*3
    float* out      = (float*)d_out;           // 8*192*128*128
    short* blob     = (short*)d_ws;            // 82944 B frag blob

    wtransform<<<(COUT * CIN * 9 + 255) / 256, 256, 0, stream>>>(Wg, blob);

    conv3x3_unshuffle_mfma<<<dim3(4096), dim3(256), 0, stream>>>(x, blob, out);
}